// Round 1
// baseline (5446.740 us; speedup 1.0000x reference)
//
#include <hip/hip_runtime.h>
#include <math.h>

// FusionShiftingGraph: two 4-layer no-residual transformer stacks + final LN.
// Round 0: faithful fp32 baseline (attention logits std ~236 at layer 1 ->
// argmax-regime softmax; bf16 would flip argmaxes and blow absmax).
//
// Segments: [0,50) [50,425) [425,800).  B=8, N=800, D=768, H=8, hd=96.

#define NTOK 800
#define ROWS 6400          // B*N
#define DIM 768
#define QKVD 2304
#define HD 96

// ---------------------------------------------------------------- embed
__global__ __launch_bounds__(256) void k_embed(const float* __restrict__ s0,
                                               const float* __restrict__ s1,
                                               const float* __restrict__ s2,
                                               float* __restrict__ x) {
  int row = blockIdx.x;            // 0..6399
  int b = row / NTOK, n = row % NTOK;
  const float* src; int ln;
  if (n < 50)       { src = s0 + ((size_t)b * 50  + n)         * DIM; ln = n; }
  else if (n < 425) { src = s1 + ((size_t)b * 375 + (n - 50))  * DIM; ln = n - 50; }
  else              { src = s2 + ((size_t)b * 375 + (n - 425)) * DIM; ln = n - 425; }
  double p = (double)(ln + 2);     // fairseq: positions start at padding_idx+1=2
  const double negk = -(9.210340371976184 / 383.0);  // -ln(10000)/(half-1)
  float* dst = x + (size_t)row * DIM;
  for (int i = 0; i < 3; i++) {
    int d = threadIdx.x + (i << 8);
    int dd = (d < 384) ? d : d - 384;
    double ang = p * exp((double)dd * negk);
    float pe = (float)((d < 384) ? sin(ang) : cos(ang));
    dst[d] = 27.712812921102035f * src[d] + pe;   // sqrt(768)*s + pe
  }
}

// ------------------------------------------------------- fp32 NT SGEMM
// C[m][n] = sum_k A[m][k] * Bw[n][k] + bias[n]
// A: MxK row-major, Bw: NxK row-major (weight layout), C: MxN.
// Block tile 128x128, BK=16, 256 threads, 8x8 micro split 2x(4+4).
__global__ __launch_bounds__(256) void k_gemm_nt(const float* __restrict__ A,
                                                 const float* __restrict__ Bw,
                                                 const float* __restrict__ bias,
                                                 float* __restrict__ C,
                                                 int M, int N, int K) {
  __shared__ float As[16][132];   // [k][m], pitch 132 -> 2-way max on writes
  __shared__ float Bs[16][132];   // [k][n]
  int tid = threadIdx.x;
  int tx = tid & 15, ty = tid >> 4;
  int m0 = blockIdx.y << 7, n0 = blockIdx.x << 7;

  float acc[2][2][4][4];
#pragma unroll
  for (int a = 0; a < 2; a++)
#pragma unroll
    for (int b2 = 0; b2 < 2; b2++)
#pragma unroll
      for (int i = 0; i < 4; i++)
#pragma unroll
        for (int j = 0; j < 4; j++) acc[a][b2][i][j] = 0.f;

  for (int k0 = 0; k0 < K; k0 += 16) {
    __syncthreads();
#pragma unroll
    for (int c0 = 0; c0 < 2; c0++) {
      int c = tid + (c0 << 8);          // 0..511
      int r = c >> 2, kg = (c & 3) << 2;
      float4 va = *(const float4*)(A + (size_t)(m0 + r) * K + k0 + kg);
      As[kg + 0][r] = va.x; As[kg + 1][r] = va.y; As[kg + 2][r] = va.z; As[kg + 3][r] = va.w;
      float4 vb = *(const float4*)(Bw + (size_t)(n0 + r) * K + k0 + kg);
      Bs[kg + 0][r] = vb.x; Bs[kg + 1][r] = vb.y; Bs[kg + 2][r] = vb.z; Bs[kg + 3][r] = vb.w;
    }
    __syncthreads();
#pragma unroll
    for (int kk = 0; kk < 16; kk++) {
      float a[2][4], b[2][4];
      float4 t;
      t = *(const float4*)&As[kk][(ty << 2)];      a[0][0]=t.x; a[0][1]=t.y; a[0][2]=t.z; a[0][3]=t.w;
      t = *(const float4*)&As[kk][64 + (ty << 2)]; a[1][0]=t.x; a[1][1]=t.y; a[1][2]=t.z; a[1][3]=t.w;
      t = *(const float4*)&Bs[kk][(tx << 2)];      b[0][0]=t.x; b[0][1]=t.y; b[0][2]=t.z; b[0][3]=t.w;
      t = *(const float4*)&Bs[kk][64 + (tx << 2)]; b[1][0]=t.x; b[1][1]=t.y; b[1][2]=t.z; b[1][3]=t.w;
#pragma unroll
      for (int i = 0; i < 4; i++)
#pragma unroll
        for (int j = 0; j < 4; j++) {
          acc[0][0][i][j] = fmaf(a[0][i], b[0][j], acc[0][0][i][j]);
          acc[0][1][i][j] = fmaf(a[0][i], b[1][j], acc[0][1][i][j]);
          acc[1][0][i][j] = fmaf(a[1][i], b[0][j], acc[1][0][i][j]);
          acc[1][1][i][j] = fmaf(a[1][i], b[1][j], acc[1][1][i][j]);
        }
    }
  }
#pragma unroll
  for (int rh = 0; rh < 2; rh++)
#pragma unroll
    for (int i = 0; i < 4; i++) {
      int row = m0 + (rh << 6) + (ty << 2) + i;
#pragma unroll
      for (int ch = 0; ch < 2; ch++) {
        int col = n0 + (ch << 6) + (tx << 2);
        float4 o;
        o.x = acc[rh][ch][i][0] + bias[col + 0];
        o.y = acc[rh][ch][i][1] + bias[col + 1];
        o.z = acc[rh][ch][i][2] + bias[col + 2];
        o.w = acc[rh][ch][i][3] + bias[col + 3];
        *(float4*)(C + (size_t)row * N + col) = o;
      }
    }
}

// ------------------------------------------------- fp32 flash attention
// Grid: 13 q-tiles x 64 (b,h).  Q-tile 64 rows; 32-key tiles over allowed
// ranges only (mask == range restriction; exp(-1e10-m) == 0 in fp32).
__global__ __launch_bounds__(256) void k_attn(const float* __restrict__ qkv,
                                              float* __restrict__ outp,
                                              int intra) {
  int t  = blockIdx.x % 13;
  int bh = blockIdx.x / 13;
  int b = bh >> 3, h = bh & 7;

  int seg, q0, qlen;
  if (t == 0)      { seg = 0; q0 = 0;                  qlen = 50; }
  else if (t <= 6) { seg = 1; q0 = 50 + ((t - 1) << 6);  qlen = (425 - q0 < 64) ? (425 - q0) : 64; }
  else             { seg = 2; q0 = 425 + ((t - 7) << 6); qlen = (800 - q0 < 64) ? (800 - q0) : 64; }

  int r0s, r0e, r1s, r1e;
  if (intra) {
    r0s = (seg == 0) ? 0 : (seg == 1) ? 50 : 425;
    r0e = (seg == 0) ? 50 : (seg == 1) ? 425 : 800;
    r1s = 0; r1e = 0;
  } else {
    if (seg == 0)      { r0s = 50; r0e = 800; r1s = 0;   r1e = 0; }
    else if (seg == 1) { r0s = 0;  r0e = 50;  r1s = 425; r1e = 800; }
    else               { r0s = 0;  r0e = 425; r1s = 0;   r1e = 0; }
  }

  __shared__ float Qs[96][64];   // [d][row]
  __shared__ float Ks[96][32];   // [d][key]
  __shared__ float Vs[32][98];   // [key][d] padded
  __shared__ float Ps[64][34];   // [row][key] padded

  int tid = threadIdx.x;
  int tx = tid & 15, ty = tid >> 4;       // 16 lanes share a row-group
  size_t base = (size_t)b * NTOK;

  // stage Q transposed (once per block)
  for (int c = tid; c < 64 * 24; c += 256) {
    int r = c & 63, dc = c >> 6;
    int q = q0 + r; q = (q > 799) ? 799 : q;   // clamp addr; garbage rows never stored
    float4 v = *(const float4*)(qkv + (base + q) * QKVD + h * HD + (dc << 2));
    Qs[(dc << 2) + 0][r] = v.x; Qs[(dc << 2) + 1][r] = v.y;
    Qs[(dc << 2) + 2][r] = v.z; Qs[(dc << 2) + 3][r] = v.w;
  }

  float m_i[4], l_i[4], o[4][3][2];
#pragma unroll
  for (int i = 0; i < 4; i++) {
    m_i[i] = -1e30f; l_i[i] = 0.f;
#pragma unroll
    for (int c = 0; c < 3; c++) { o[i][c][0] = 0.f; o[i][c][1] = 0.f; }
  }
  const float sm = 0.10206207261596575f;   // 96^-0.5

  for (int rr = 0; rr < 2; rr++) {
    int rs = rr ? r1s : r0s, re = rr ? r1e : r0e;
    for (int kt = rs; kt < re; kt += 32) {
      __syncthreads();
      // stage K transposed
      for (int c = tid; c < 768; c += 256) {
        int kc = c & 31, dc = c >> 5;
        int key = kt + kc; key = (key > 799) ? 799 : key;
        float4 v = *(const float4*)(qkv + (base + key) * QKVD + DIM + h * HD + (dc << 2));
        Ks[(dc << 2) + 0][kc] = v.x; Ks[(dc << 2) + 1][kc] = v.y;
        Ks[(dc << 2) + 2][kc] = v.z; Ks[(dc << 2) + 3][kc] = v.w;
      }
      // stage V direct (padded pitch)
      for (int c = tid; c < 768; c += 256) {
        int kc = c & 31, dc = c >> 5;
        int key = kt + kc; key = (key > 799) ? 799 : key;
        float4 v = *(const float4*)(qkv + (base + key) * QKVD + 2 * DIM + h * HD + (dc << 2));
        *(float2*)&Vs[kc][(dc << 2) + 0] = make_float2(v.x, v.y);
        *(float2*)&Vs[kc][(dc << 2) + 2] = make_float2(v.z, v.w);
      }
      __syncthreads();

      // S = Q K^T : thread rows ty*4+i, cols tx*2+j
      float s[4][2] = {{0.f,0.f},{0.f,0.f},{0.f,0.f},{0.f,0.f}};
      for (int d = 0; d < 96; d++) {
        float4 a4 = *(const float4*)&Qs[d][(ty << 2)];
        float2 k2 = *(const float2*)&Ks[d][(tx << 1)];
        s[0][0] = fmaf(a4.x, k2.x, s[0][0]); s[0][1] = fmaf(a4.x, k2.y, s[0][1]);
        s[1][0] = fmaf(a4.y, k2.x, s[1][0]); s[1][1] = fmaf(a4.y, k2.y, s[1][1]);
        s[2][0] = fmaf(a4.z, k2.x, s[2][0]); s[2][1] = fmaf(a4.z, k2.y, s[2][1]);
        s[3][0] = fmaf(a4.w, k2.x, s[3][0]); s[3][1] = fmaf(a4.w, k2.y, s[3][1]);
      }
      float p[4][2], mx[4];
#pragma unroll
      for (int i = 0; i < 4; i++) {
#pragma unroll
        for (int j = 0; j < 2; j++) {
          float sv = s[i][j] * sm;
          int key = kt + (tx << 1) + j;
          if (key >= re) sv = -1e30f;     // tail of last key tile
          s[i][j] = sv;
        }
        mx[i] = fmaxf(s[i][0], s[i][1]);
      }
#pragma unroll
      for (int off = 1; off < 16; off <<= 1) {
#pragma unroll
        for (int i = 0; i < 4; i++) mx[i] = fmaxf(mx[i], __shfl_xor(mx[i], off, 64));
      }
      float al[4], rsum[4];
#pragma unroll
      for (int i = 0; i < 4; i++) {
        float mn = fmaxf(m_i[i], mx[i]);
        al[i] = expf(m_i[i] - mn);
        m_i[i] = mn;
        p[i][0] = expf(s[i][0] - mn);
        p[i][1] = expf(s[i][1] - mn);
        rsum[i] = p[i][0] + p[i][1];
      }
#pragma unroll
      for (int off = 1; off < 16; off <<= 1) {
#pragma unroll
        for (int i = 0; i < 4; i++) rsum[i] += __shfl_xor(rsum[i], off, 64);
      }
#pragma unroll
      for (int i = 0; i < 4; i++) {
        l_i[i] = l_i[i] * al[i] + rsum[i];
        Ps[(ty << 2) + i][(tx << 1) + 0] = p[i][0];
        Ps[(ty << 2) + i][(tx << 1) + 1] = p[i][1];
#pragma unroll
        for (int c = 0; c < 3; c++) { o[i][c][0] *= al[i]; o[i][c][1] *= al[i]; }
      }
      __syncthreads();

      // O += P V : rows ty*4+i, cols c*32 + tx*2 + j
#pragma unroll
      for (int k2i = 0; k2i < 16; k2i++) {
        int k = k2i << 1;
        float2 pp[4];
        pp[0] = *(const float2*)&Ps[(ty << 2) + 0][k];
        pp[1] = *(const float2*)&Ps[(ty << 2) + 1][k];
        pp[2] = *(const float2*)&Ps[(ty << 2) + 2][k];
        pp[3] = *(const float2*)&Ps[(ty << 2) + 3][k];
#pragma unroll
        for (int kk = 0; kk < 2; kk++) {
          float pv[4];
          pv[0] = kk ? pp[0].y : pp[0].x;
          pv[1] = kk ? pp[1].y : pp[1].x;
          pv[2] = kk ? pp[2].y : pp[2].x;
          pv[3] = kk ? pp[3].y : pp[3].x;
          float2 v0 = *(const float2*)&Vs[k + kk][(tx << 1)];
          float2 v1 = *(const float2*)&Vs[k + kk][32 + (tx << 1)];
          float2 v2 = *(const float2*)&Vs[k + kk][64 + (tx << 1)];
#pragma unroll
          for (int i = 0; i < 4; i++) {
            o[i][0][0] = fmaf(pv[i], v0.x, o[i][0][0]);
            o[i][0][1] = fmaf(pv[i], v0.y, o[i][0][1]);
            o[i][1][0] = fmaf(pv[i], v1.x, o[i][1][0]);
            o[i][1][1] = fmaf(pv[i], v1.y, o[i][1][1]);
            o[i][2][0] = fmaf(pv[i], v2.x, o[i][2][0]);
            o[i][2][1] = fmaf(pv[i], v2.y, o[i][2][1]);
          }
        }
      }
    }
  }

#pragma unroll
  for (int i = 0; i < 4; i++) {
    int r = (ty << 2) + i;
    if (r < qlen) {
      float inv = 1.0f / l_i[i];
      float* orow = outp + (base + q0 + r) * DIM + h * HD;
#pragma unroll
      for (int c = 0; c < 3; c++) {
        *(float2*)&orow[(c << 5) + (tx << 1)] =
            make_float2(o[i][c][0] * inv, o[i][c][1] * inv);
      }
    }
  }
}

// ---------------------------------------------------------------- layernorm
__global__ __launch_bounds__(256) void k_ln(const float* __restrict__ x,
                                            const float* __restrict__ g,
                                            const float* __restrict__ be,
                                            float* __restrict__ outp) {
  int row = blockIdx.x;
  const float* xr = x + (size_t)row * DIM;
  float v[3]; float s = 0.f;
#pragma unroll
  for (int i = 0; i < 3; i++) { v[i] = xr[threadIdx.x + (i << 8)]; s += v[i]; }
#pragma unroll
  for (int off = 1; off < 64; off <<= 1) s += __shfl_xor(s, off, 64);
  __shared__ float red[4];
  int wv = threadIdx.x >> 6;
  if ((threadIdx.x & 63) == 0) red[wv] = s;
  __syncthreads();
  float mu = (red[0] + red[1] + red[2] + red[3]) * (1.0f / 768.0f);
  float sq = 0.f;
#pragma unroll
  for (int i = 0; i < 3; i++) { float d2 = v[i] - mu; sq += d2 * d2; }
#pragma unroll
  for (int off = 1; off < 64; off <<= 1) sq += __shfl_xor(sq, off, 64);
  __syncthreads();
  if ((threadIdx.x & 63) == 0) red[wv] = sq;
  __syncthreads();
  float var = (red[0] + red[1] + red[2] + red[3]) * (1.0f / 768.0f);
  float rstd = rsqrtf(var + 1e-5f);
  float* orow = outp + (size_t)row * DIM;
#pragma unroll
  for (int i = 0; i < 3; i++) {
    int d = threadIdx.x + (i << 8);
    orow[d] = (v[i] - mu) * rstd * g[d] + be[d];
  }
}

// ---------------------------------------------------------------- launch
extern "C" void kernel_launch(void* const* d_in, const int* in_sizes, int n_in,
                              void* d_out, int out_size, void* d_ws, size_t ws_size,
                              hipStream_t stream) {
  const float* seq0 = (const float*)d_in[0];
  const float* seq1 = (const float*)d_in[1];
  const float* seq2 = (const float*)d_in[2];

  // workspace layout (fp32): x0 | qkv | att | X   == ~118 MB
  float* x0   = (float*)d_ws;
  float* qkvb = x0   + (size_t)ROWS * DIM;
  float* att  = qkvb + (size_t)ROWS * QKVD;
  float* X    = att  + (size_t)ROWS * DIM;

  k_embed<<<ROWS, 256, 0, stream>>>(seq0, seq1, seq2, x0);

  for (int g = 0; g < 2; g++) {           // g=0: inter, g=1: intra
    const float* w_in  = (const float*)d_in[3 + 6 * g];
    const float* b_in  = (const float*)d_in[4 + 6 * g];
    const float* w_out = (const float*)d_in[5 + 6 * g];
    const float* b_out = (const float*)d_in[6 + 6 * g];
    const float* ln_g  = (const float*)d_in[7 + 6 * g];
    const float* ln_b  = (const float*)d_in[8 + 6 * g];
    for (int l = 0; l < 4; l++) {
      const float* xin = (l == 0) ? x0 : X;
      k_gemm_nt<<<dim3(QKVD / 128, ROWS / 128), 256, 0, stream>>>(
          xin, w_in + (size_t)l * QKVD * DIM, b_in + (size_t)l * QKVD,
          qkvb, ROWS, QKVD, DIM);
      k_attn<<<13 * 64, 256, 0, stream>>>(qkvb, att, g);
      k_gemm_nt<<<dim3(DIM / 128, ROWS / 128), 256, 0, stream>>>(
          att, w_out + (size_t)l * DIM * DIM, b_out + (size_t)l * DIM,
          X, ROWS, DIM, DIM);
    }
    k_ln<<<ROWS, 256, 0, stream>>>(X, ln_g, ln_b,
                                   (float*)d_out + (size_t)g * ROWS * DIM);
  }
}

// Round 2
// 2935.054 us; speedup vs baseline: 1.8558x; 1.8558x over previous
//
#include <hip/hip_runtime.h>
#include <math.h>

// FusionShiftingGraph: two 4-layer no-residual transformer stacks + final LN.
// Round 2: GEMMs via 3-plane split-bf16 MFMA (fp32-equivalent accuracy:
// logits are argmax-regime, need rel err << 3e-3; 3-plane gives ~1e-5).
// Attention: fp32, register-prefetch double-buffer, 2 barriers/tile.
//
// Segments: [0,50) [50,425) [425,800).  B=8, N=800, D=768, H=8, hd=96.

#define NTOK 800
#define ROWS 6400          // B*N
#define DIM 768
#define QKVD 2304
#define HD 96

typedef unsigned short u16;
typedef unsigned int u32;
using bf16x8 = __attribute__((ext_vector_type(8))) short;   // 8 bf16 (4 VGPRs)
using f32x4  = __attribute__((ext_vector_type(4))) float;

__device__ __forceinline__ u16 f2bf(float x) {            // RNE fp32->bf16
  union { float f; u32 u; } v; v.f = x;
  u32 r = v.u + 0x7fffu + ((v.u >> 16) & 1u);
  return (u16)(r >> 16);
}
__device__ __forceinline__ float bf2f(u16 h) {
  union { u32 u; float f; } v; v.u = ((u32)h) << 16;
  return v.f;
}
__device__ __forceinline__ void async16(const u16* g, u16* l) {
  __builtin_amdgcn_global_load_lds((const __attribute__((address_space(1))) u32*)g,
                                   (__attribute__((address_space(3))) u32*)l,
                                   16, 0, 0);
}

// ---------------------------------------------------------------- embed
__global__ __launch_bounds__(256) void k_embed(const float* __restrict__ s0,
                                               const float* __restrict__ s1,
                                               const float* __restrict__ s2,
                                               float* __restrict__ x) {
  int row = blockIdx.x;            // 0..6399
  int b = row / NTOK, n = row % NTOK;
  const float* src; int ln;
  if (n < 50)       { src = s0 + ((size_t)b * 50  + n)         * DIM; ln = n; }
  else if (n < 425) { src = s1 + ((size_t)b * 375 + (n - 50))  * DIM; ln = n - 50; }
  else              { src = s2 + ((size_t)b * 375 + (n - 425)) * DIM; ln = n - 425; }
  double p = (double)(ln + 2);     // fairseq: positions start at padding_idx+1=2
  const double negk = -(9.210340371976184 / 383.0);  // -ln(10000)/(half-1)
  float* dst = x + (size_t)row * DIM;
  for (int i = 0; i < 3; i++) {
    int d = threadIdx.x + (i << 8);
    int dd = (d < 384) ? d : d - 384;
    double ang = p * exp((double)dd * negk);
    float pe = (float)((d < 384) ? sin(ang) : cos(ang));
    dst[d] = 27.712812921102035f * src[d] + pe;   // sqrt(768)*s + pe
  }
}

// ------------------------------------------------- fp32 -> (hi,lo) bf16 planes
__global__ __launch_bounds__(256) void k_conv(const float* __restrict__ x,
                                              u16* __restrict__ hi,
                                              u16* __restrict__ lo, int n8) {
  int i = blockIdx.x * 256 + threadIdx.x;   // 8 elems / thread
  if (i >= n8) return;
  float4 a = ((const float4*)x)[i * 2];
  float4 b = ((const float4*)x)[i * 2 + 1];
  float v[8] = {a.x, a.y, a.z, a.w, b.x, b.y, b.z, b.w};
  u32 hp[4], lp[4];
#pragma unroll
  for (int j = 0; j < 4; j++) {
    u16 h0 = f2bf(v[2 * j]), h1 = f2bf(v[2 * j + 1]);
    u16 l0 = f2bf(v[2 * j] - bf2f(h0));
    u16 l1 = f2bf(v[2 * j + 1] - bf2f(h1));
    hp[j] = (u32)h0 | ((u32)h1 << 16);
    lp[j] = (u32)l0 | ((u32)l1 << 16);
  }
  ((uint4*)hi)[i] = make_uint4(hp[0], hp[1], hp[2], hp[3]);
  ((uint4*)lo)[i] = make_uint4(lp[0], lp[1], lp[2], lp[3]);
}

// ------------------------------------------- split-bf16 MFMA NT GEMM
// C[m][n] = sum_k A[m][k]*W[n][k] + bias[n], via 3 MFMA planes.
// 128x128 tile, BK=32, 256 thr = 4 waves (2x2 of 64x64), 16x16x32 MFMA.
// LDS image per region: 128 rows x 32 cols bf16, column-chunk XOR-swizzled
// (chunk ^= (row>>1)&3) at the *global source* so global_load_lds stays linear
// while ds_read_b128 fragment reads hit only free 2-way conflicts.
__global__ __launch_bounds__(256) void k_gemm_mfma(
    const u16* __restrict__ Ah, const u16* __restrict__ Al,
    const u16* __restrict__ Bh, const u16* __restrict__ Bl,
    const float* __restrict__ bias, float* __restrict__ C,
    int M, int N, int K) {
  __shared__ u16 sm[4 * 4096];       // Ah | Al | Bh | Bl  (8KB each)
  int tid = threadIdx.x;
  int wave = tid >> 6, lane = tid & 63;
  int m0 = blockIdx.y << 7, n0 = blockIdx.x << 7;
  int wr = wave >> 1, wc = wave & 1;
  int l15 = lane & 15, quad = lane >> 4;

  f32x4 acc[4][4];
#pragma unroll
  for (int i = 0; i < 4; i++)
#pragma unroll
    for (int j = 0; j < 4; j++) acc[i][j] = (f32x4){0.f, 0.f, 0.f, 0.f};

  const u16* srcs[4] = {Ah + (size_t)m0 * K, Al + (size_t)m0 * K,
                        Bh + (size_t)n0 * K, Bl + (size_t)n0 * K};
  // staging: 16B chunk index li -> row=li>>2, q=li&3, source chunk q^((row>>1)&3)
  int li0 = wave * 64 + lane;
  int li1 = li0 + 256;
  int r0 = li0 >> 2, q0 = (li0 & 3) ^ ((r0 >> 1) & 3);
  int r1 = li1 >> 2, q1 = (li1 & 3) ^ ((r1 >> 1) & 3);
  size_t g0 = (size_t)r0 * K + q0 * 8;
  size_t g1 = (size_t)r1 * K + q1 * 8;

  for (int kt = 0; kt < K; kt += 32) {
    __syncthreads();
#pragma unroll
    for (int ri = 0; ri < 4; ri++) {
      const u16* s = srcs[ri] + kt;
      async16(s + g0, &sm[ri * 4096 + wave * 512]);
      async16(s + g1, &sm[ri * 4096 + 2048 + wave * 512]);
    }
    __syncthreads();   // drains vmcnt -> LDS image valid

    bf16x8 ah[4], al[4], bh[4], bl[4];
#pragma unroll
    for (int i = 0; i < 4; i++) {
      int ra = wr * 64 + i * 16 + l15;
      int qa = (quad ^ ((ra >> 1) & 3)) * 8;
      ah[i] = *(const bf16x8*)&sm[0 * 4096 + ra * 32 + qa];
      al[i] = *(const bf16x8*)&sm[1 * 4096 + ra * 32 + qa];
      int rb = wc * 64 + i * 16 + l15;
      int qb = (quad ^ ((rb >> 1) & 3)) * 8;
      bh[i] = *(const bf16x8*)&sm[2 * 4096 + rb * 32 + qb];
      bl[i] = *(const bf16x8*)&sm[3 * 4096 + rb * 32 + qb];
    }
#pragma unroll
    for (int i = 0; i < 4; i++)
#pragma unroll
      for (int j = 0; j < 4; j++) {
        acc[i][j] = __builtin_amdgcn_mfma_f32_16x16x32_bf16(ah[i], bh[j], acc[i][j], 0, 0, 0);
        acc[i][j] = __builtin_amdgcn_mfma_f32_16x16x32_bf16(ah[i], bl[j], acc[i][j], 0, 0, 0);
        acc[i][j] = __builtin_amdgcn_mfma_f32_16x16x32_bf16(al[i], bh[j], acc[i][j], 0, 0, 0);
      }
  }

  // epilogue: C/D layout col=lane&15, row=quad*4+reg (m89/m91-verified)
#pragma unroll
  for (int i = 0; i < 4; i++) {
    int row0 = m0 + wr * 64 + i * 16 + quad * 4;
#pragma unroll
    for (int j = 0; j < 4; j++) {
      int col = n0 + wc * 64 + j * 16 + l15;
      float bv = bias[col];
#pragma unroll
      for (int r = 0; r < 4; r++)
        C[(size_t)(row0 + r) * N + col] = acc[i][j][r] + bv;
    }
  }
}

// ------------------------------------------- fp32 flash attention (prefetch)
// Grid: 13 q-tiles x 64 (b,h).  Q-tile 64 rows; 32-key tiles over allowed
// ranges only.  K/V for tile i+1 prefetched into regs during tile-i compute;
// 2 barriers/tile; P exchange is intra-wave (no barrier, clobber only).
__global__ __launch_bounds__(256) void k_attn(const float* __restrict__ qkv,
                                              float* __restrict__ outp,
                                              int intra) {
  int t  = blockIdx.x % 13;
  int bh = blockIdx.x / 13;
  int b = bh >> 3, h = bh & 7;

  int seg, q0, qlen;
  if (t == 0)      { seg = 0; q0 = 0;                  qlen = 50; }
  else if (t <= 6) { seg = 1; q0 = 50 + ((t - 1) << 6);  qlen = (425 - q0 < 64) ? (425 - q0) : 64; }
  else             { seg = 2; q0 = 425 + ((t - 7) << 6); qlen = (800 - q0 < 64) ? (800 - q0) : 64; }

  int r0s, r0e, r1s, r1e;
  if (intra) {
    r0s = (seg == 0) ? 0 : (seg == 1) ? 50 : 425;
    r0e = (seg == 0) ? 50 : (seg == 1) ? 425 : 800;
    r1s = 0; r1e = 0;
  } else {
    if (seg == 0)      { r0s = 50; r0e = 800; r1s = 0;   r1e = 0; }
    else if (seg == 1) { r0s = 0;  r0e = 50;  r1s = 425; r1e = 800; }
    else               { r0s = 0;  r0e = 425; r1s = 0;   r1e = 0; }
  }
  int n0t = (r0e - r0s + 31) >> 5;
  int n1t = (r1e - r1s + 31) >> 5;
  int nkt = n0t + n1t;

  __shared__ float Qs[96][64];   // [d][row]
  __shared__ float Ks[96][32];   // [d][key]
  __shared__ float Vs[32][98];   // [key][d] padded
  __shared__ float Ps[64][34];   // [row][key] padded (even pitch: float2 align)

  int tid = threadIdx.x;
  int tx = tid & 15, ty = tid >> 4;
  size_t base = (size_t)b * NTOK;

  // stage Q transposed (once)
  for (int c = tid; c < 64 * 24; c += 256) {
    int r = c & 63, dc = c >> 6;
    int q = q0 + r; q = (q > 799) ? 799 : q;
    float4 v = *(const float4*)(qkv + (base + q) * QKVD + h * HD + (dc << 2));
    Qs[(dc << 2) + 0][r] = v.x; Qs[(dc << 2) + 1][r] = v.y;
    Qs[(dc << 2) + 2][r] = v.z; Qs[(dc << 2) + 3][r] = v.w;
  }

  float m_i[4], l_i[4], o[4][3][2];
#pragma unroll
  for (int i = 0; i < 4; i++) {
    m_i[i] = -1e30f; l_i[i] = 0.f;
#pragma unroll
    for (int c = 0; c < 3; c++) { o[i][c][0] = 0.f; o[i][c][1] = 0.f; }
  }
  const float sm = 0.10206207261596575f;   // 96^-0.5

  int kcc = tid & 31, dcc0 = tid >> 5;     // staging coords (j adds 8 to dcc)
  float4 kreg[3], vreg[3];
  // prefetch tile 0
  {
    int ks0 = (0 < n0t) ? r0s : r1s;
#pragma unroll
    for (int j = 0; j < 3; j++) {
      int dcc = dcc0 + (j << 3);
      int key = ks0 + kcc; key = (key > 799) ? 799 : key;
      kreg[j] = *(const float4*)(qkv + (base + key) * QKVD + DIM + h * HD + (dcc << 2));
      vreg[j] = *(const float4*)(qkv + (base + key) * QKVD + 2 * DIM + h * HD + (dcc << 2));
    }
  }

  for (int it = 0; it < nkt; it++) {
    int kt = (it < n0t) ? (r0s + (it << 5)) : (r1s + ((it - n0t) << 5));
    int re = (it < n0t) ? r0e : r1e;

    __syncthreads();    // prev compute done; prev prefetch drained
#pragma unroll
    for (int j = 0; j < 3; j++) {
      int dcc = dcc0 + (j << 3);
      Ks[(dcc << 2) + 0][kcc] = kreg[j].x; Ks[(dcc << 2) + 1][kcc] = kreg[j].y;
      Ks[(dcc << 2) + 2][kcc] = kreg[j].z; Ks[(dcc << 2) + 3][kcc] = kreg[j].w;
      Vs[kcc][(dcc << 2) + 0] = vreg[j].x; Vs[kcc][(dcc << 2) + 1] = vreg[j].y;
      Vs[kcc][(dcc << 2) + 2] = vreg[j].z; Vs[kcc][(dcc << 2) + 3] = vreg[j].w;
    }
    __syncthreads();    // staging visible

    // prefetch next tile (after barrier so its vmcnt isn't drained there)
    {
      int itn = (it + 1 < nkt) ? it + 1 : it;
      int ksn = (itn < n0t) ? (r0s + (itn << 5)) : (r1s + ((itn - n0t) << 5));
#pragma unroll
      for (int j = 0; j < 3; j++) {
        int dcc = dcc0 + (j << 3);
        int key = ksn + kcc; key = (key > 799) ? 799 : key;
        kreg[j] = *(const float4*)(qkv + (base + key) * QKVD + DIM + h * HD + (dcc << 2));
        vreg[j] = *(const float4*)(qkv + (base + key) * QKVD + 2 * DIM + h * HD + (dcc << 2));
      }
    }

    // S = Q K^T : thread rows ty*4+i, cols tx*2+j
    float s[4][2] = {{0.f,0.f},{0.f,0.f},{0.f,0.f},{0.f,0.f}};
    for (int d = 0; d < 96; d++) {
      float4 a4 = *(const float4*)&Qs[d][(ty << 2)];
      float2 k2 = *(const float2*)&Ks[d][(tx << 1)];
      s[0][0] = fmaf(a4.x, k2.x, s[0][0]); s[0][1] = fmaf(a4.x, k2.y, s[0][1]);
      s[1][0] = fmaf(a4.y, k2.x, s[1][0]); s[1][1] = fmaf(a4.y, k2.y, s[1][1]);
      s[2][0] = fmaf(a4.z, k2.x, s[2][0]); s[2][1] = fmaf(a4.z, k2.y, s[2][1]);
      s[3][0] = fmaf(a4.w, k2.x, s[3][0]); s[3][1] = fmaf(a4.w, k2.y, s[3][1]);
    }
    float p[4][2], mx[4];
#pragma unroll
    for (int i = 0; i < 4; i++) {
#pragma unroll
      for (int j = 0; j < 2; j++) {
        float sv = s[i][j] * sm;
        int key = kt + (tx << 1) + j;
        if (key >= re) sv = -1e30f;
        s[i][j] = sv;
      }
      mx[i] = fmaxf(s[i][0], s[i][1]);
    }
#pragma unroll
    for (int off = 1; off < 16; off <<= 1) {
#pragma unroll
      for (int i = 0; i < 4; i++) mx[i] = fmaxf(mx[i], __shfl_xor(mx[i], off, 64));
    }
    float al[4], rsum[4];
#pragma unroll
    for (int i = 0; i < 4; i++) {
      float mn = fmaxf(m_i[i], mx[i]);
      al[i] = expf(m_i[i] - mn);
      m_i[i] = mn;
      p[i][0] = expf(s[i][0] - mn);
      p[i][1] = expf(s[i][1] - mn);
      rsum[i] = p[i][0] + p[i][1];
    }
#pragma unroll
    for (int off = 1; off < 16; off <<= 1) {
#pragma unroll
      for (int i = 0; i < 4; i++) rsum[i] += __shfl_xor(rsum[i], off, 64);
    }
#pragma unroll
    for (int i = 0; i < 4; i++) {
      l_i[i] = l_i[i] * al[i] + rsum[i];
      Ps[(ty << 2) + i][(tx << 1) + 0] = p[i][0];
      Ps[(ty << 2) + i][(tx << 1) + 1] = p[i][1];
#pragma unroll
      for (int c = 0; c < 3; c++) { o[i][c][0] *= al[i]; o[i][c][1] *= al[i]; }
    }
    // P exchange is intra-wave (rows ty*4+i owned & read by same 16-lane grp):
    // HW keeps wave LDS ops in order; just stop compiler reordering.
    asm volatile("" ::: "memory");

    // O += P V
#pragma unroll
    for (int k2i = 0; k2i < 16; k2i++) {
      int k = k2i << 1;
      float2 pp[4];
      pp[0] = *(const float2*)&Ps[(ty << 2) + 0][k];
      pp[1] = *(const float2*)&Ps[(ty << 2) + 1][k];
      pp[2] = *(const float2*)&Ps[(ty << 2) + 2][k];
      pp[3] = *(const float2*)&Ps[(ty << 2) + 3][k];
#pragma unroll
      for (int kk = 0; kk < 2; kk++) {
        float pv[4];
        pv[0] = kk ? pp[0].y : pp[0].x;
        pv[1] = kk ? pp[1].y : pp[1].x;
        pv[2] = kk ? pp[2].y : pp[2].x;
        pv[3] = kk ? pp[3].y : pp[3].x;
        float2 v0 = *(const float2*)&Vs[k + kk][(tx << 1)];
        float2 v1 = *(const float2*)&Vs[k + kk][32 + (tx << 1)];
        float2 v2 = *(const float2*)&Vs[k + kk][64 + (tx << 1)];
#pragma unroll
        for (int i = 0; i < 4; i++) {
          o[i][0][0] = fmaf(pv[i], v0.x, o[i][0][0]);
          o[i][0][1] = fmaf(pv[i], v0.y, o[i][0][1]);
          o[i][1][0] = fmaf(pv[i], v1.x, o[i][1][0]);
          o[i][1][1] = fmaf(pv[i], v1.y, o[i][1][1]);
          o[i][2][0] = fmaf(pv[i], v2.x, o[i][2][0]);
          o[i][2][1] = fmaf(pv[i], v2.y, o[i][2][1]);
        }
      }
    }
  }

#pragma unroll
  for (int i = 0; i < 4; i++) {
    int r = (ty << 2) + i;
    if (r < qlen) {
      float inv = 1.0f / l_i[i];
      float* orow = outp + (base + q0 + r) * DIM + h * HD;
#pragma unroll
      for (int c = 0; c < 3; c++) {
        *(float2*)&orow[(c << 5) + (tx << 1)] =
            make_float2(o[i][c][0] * inv, o[i][c][1] * inv);
      }
    }
  }
}

// ---------------------------------------------------------------- layernorm
__global__ __launch_bounds__(256) void k_ln(const float* __restrict__ x,
                                            const float* __restrict__ g,
                                            const float* __restrict__ be,
                                            float* __restrict__ outp) {
  int row = blockIdx.x;
  const float* xr = x + (size_t)row * DIM;
  float v[3]; float s = 0.f;
#pragma unroll
  for (int i = 0; i < 3; i++) { v[i] = xr[threadIdx.x + (i << 8)]; s += v[i]; }
#pragma unroll
  for (int off = 1; off < 64; off <<= 1) s += __shfl_xor(s, off, 64);
  __shared__ float red[4];
  int wv = threadIdx.x >> 6;
  if ((threadIdx.x & 63) == 0) red[wv] = s;
  __syncthreads();
  float mu = (red[0] + red[1] + red[2] + red[3]) * (1.0f / 768.0f);
  float sq = 0.f;
#pragma unroll
  for (int i = 0; i < 3; i++) { float d2 = v[i] - mu; sq += d2 * d2; }
#pragma unroll
  for (int off = 1; off < 64; off <<= 1) sq += __shfl_xor(sq, off, 64);
  __syncthreads();
  if ((threadIdx.x & 63) == 0) red[wv] = sq;
  __syncthreads();
  float var = (red[0] + red[1] + red[2] + red[3]) * (1.0f / 768.0f);
  float rstd = rsqrtf(var + 1e-5f);
  float* orow = outp + (size_t)row * DIM;
#pragma unroll
  for (int i = 0; i < 3; i++) {
    int d = threadIdx.x + (i << 8);
    orow[d] = (v[i] - mu) * rstd * g[d] + be[d];
  }
}

// ---------------------------------------------------------------- launch
extern "C" void kernel_launch(void* const* d_in, const int* in_sizes, int n_in,
                              void* d_out, int out_size, void* d_ws, size_t ws_size,
                              hipStream_t stream) {
  const float* seq0 = (const float*)d_in[0];
  const float* seq1 = (const float*)d_in[1];
  const float* seq2 = (const float*)d_in[2];

  const size_t NX   = (size_t)ROWS * DIM;    // 4,915,200
  const size_t NQKV = (size_t)ROWS * QKVD;   // 14,745,600
  const int WIN_N   = QKVD * DIM;            // 1,769,472
  const int WOUT_N  = DIM * DIM;             //   589,824

  // ws layout (119.2 MiB): x0 | qkv | att | X | WPh | WPl
  // plane buffers overlap: P1(hi,lo) lives in att region, P2 in x0 region.
  float* x0   = (float*)d_ws;
  float* qkvb = x0   + NX;
  float* att  = qkvb + NQKV;
  float* X    = att  + NX;
  u16*   WPh  = (u16*)(X + NX);
  u16*   WPl  = WPh + WIN_N;
  u16*   P1h  = (u16*)att;  u16* P1l = P1h + NX;
  u16*   P2h  = (u16*)x0;   u16* P2l = P2h + NX;

  for (int g = 0; g < 2; g++) {           // g=0: inter, g=1: intra
    const float* w_in  = (const float*)d_in[3 + 6 * g];
    const float* b_in  = (const float*)d_in[4 + 6 * g];
    const float* w_out = (const float*)d_in[5 + 6 * g];
    const float* b_out = (const float*)d_in[6 + 6 * g];
    const float* ln_g  = (const float*)d_in[7 + 6 * g];
    const float* ln_b  = (const float*)d_in[8 + 6 * g];

    // x0 region doubles as P2; re-embed per graph
    k_embed<<<ROWS, 256, 0, stream>>>(seq0, seq1, seq2, x0);

    for (int l = 0; l < 4; l++) {
      const float* xin = (l == 0) ? x0 : X;
      // A planes into att region (free until k_attn writes it)
      k_conv<<<(int)(NX / 8 / 256), 256, 0, stream>>>(xin, P1h, P1l, (int)(NX / 8));
      k_conv<<<WIN_N / 8 / 256, 256, 0, stream>>>(
          w_in + (size_t)l * WIN_N, WPh, WPl, WIN_N / 8);
      k_gemm_mfma<<<dim3(QKVD / 128, ROWS / 128), 256, 0, stream>>>(
          P1h, P1l, WPh, WPl, b_in + (size_t)l * QKVD, qkvb, ROWS, QKVD, DIM);

      k_attn<<<13 * 64, 256, 0, stream>>>(qkvb, att, g);

      // A planes into x0 region (x0 consumed after layer-0 conv)
      k_conv<<<(int)(NX / 8 / 256), 256, 0, stream>>>(att, P2h, P2l, (int)(NX / 8));
      k_conv<<<WOUT_N / 8 / 256, 256, 0, stream>>>(
          w_out + (size_t)l * WOUT_N, WPh, WPl, WOUT_N / 8);
      k_gemm_mfma<<<dim3(DIM / 128, ROWS / 128), 256, 0, stream>>>(
          P2h, P2l, WPh, WPl, b_out + (size_t)l * DIM, X, ROWS, DIM, DIM);
    }
    k_ln<<<ROWS, 256, 0, stream>>>(X, ln_g, ln_b,
                                   (float*)d_out + (size_t)g * ROWS * DIM);
  }
}

// Round 3
// 2008.250 us; speedup vs baseline: 2.7122x; 1.4615x over previous
//
#include <hip/hip_runtime.h>
#include <math.h>

// FusionShiftingGraph: two 4-layer no-residual transformer stacks + final LN.
// Round 3: attention moved to split-bf16 MFMA (Q RNE 2-plane, K/V/P trunc
// 2-plane; rel err ~2^-16 vs argmax-flip budget ~3e-3). V pre-transposed to
// padded key space (64/384/384) for aligned async16 staging. GEMMs unchanged
// (3-plane split-bf16 MFMA, r2-proven).
//
// Segments: [0,50) [50,425) [425,800).  B=8, N=800, D=768, H=8, hd=96.

#define NTOK 800
#define ROWS 6400          // B*N
#define DIM 768
#define QKVD 2304
#define HD 96
#define KPAD 832           // padded key space: [0,64)+[64,448)+[448,832)

typedef unsigned short u16;
typedef unsigned int u32;
using bf16x8 = __attribute__((ext_vector_type(8))) short;   // 8 bf16 (4 VGPRs)
using f32x4  = __attribute__((ext_vector_type(4))) float;

__device__ __forceinline__ u16 f2bf(float x) {            // RNE fp32->bf16
  union { float f; u32 u; } v; v.f = x;
  u32 r = v.u + 0x7fffu + ((v.u >> 16) & 1u);
  return (u16)(r >> 16);
}
__device__ __forceinline__ float bf2f(u16 h) {
  union { u32 u; float f; } v; v.u = ((u32)h) << 16;
  return v.f;
}
__device__ __forceinline__ u32 asu(float x) { union { float f; u32 u; } v; v.f = x; return v.u; }
__device__ __forceinline__ float asf(u32 x) { union { u32 u; float f; } v; v.u = x; return v.f; }
__device__ __forceinline__ void async16(const u16* g, u16* l) {
  __builtin_amdgcn_global_load_lds((const __attribute__((address_space(1))) u32*)g,
                                   (__attribute__((address_space(3))) u32*)l,
                                   16, 0, 0);
}

// ---------------------------------------------------------------- embed
__global__ __launch_bounds__(256) void k_embed(const float* __restrict__ s0,
                                               const float* __restrict__ s1,
                                               const float* __restrict__ s2,
                                               float* __restrict__ x) {
  int row = blockIdx.x;            // 0..6399
  int b = row / NTOK, n = row % NTOK;
  const float* src; int ln;
  if (n < 50)       { src = s0 + ((size_t)b * 50  + n)         * DIM; ln = n; }
  else if (n < 425) { src = s1 + ((size_t)b * 375 + (n - 50))  * DIM; ln = n - 50; }
  else              { src = s2 + ((size_t)b * 375 + (n - 425)) * DIM; ln = n - 425; }
  double p = (double)(ln + 2);     // fairseq: positions start at padding_idx+1=2
  const double negk = -(9.210340371976184 / 383.0);  // -ln(10000)/(half-1)
  float* dst = x + (size_t)row * DIM;
  for (int i = 0; i < 3; i++) {
    int d = threadIdx.x + (i << 8);
    int dd = (d < 384) ? d : d - 384;
    double ang = p * exp((double)dd * negk);
    float pe = (float)((d < 384) ? sin(ang) : cos(ang));
    dst[d] = 27.712812921102035f * src[d] + pe;   // sqrt(768)*s + pe
  }
}

// ------------------------------------------------- fp32 -> (hi,lo) bf16 planes
__global__ __launch_bounds__(256) void k_conv(const float* __restrict__ x,
                                              u16* __restrict__ hi,
                                              u16* __restrict__ lo, int n8) {
  int i = blockIdx.x * 256 + threadIdx.x;   // 8 elems / thread
  if (i >= n8) return;
  float4 a = ((const float4*)x)[i * 2];
  float4 b = ((const float4*)x)[i * 2 + 1];
  float v[8] = {a.x, a.y, a.z, a.w, b.x, b.y, b.z, b.w};
  u32 hp[4], lp[4];
#pragma unroll
  for (int j = 0; j < 4; j++) {
    u16 h0 = f2bf(v[2 * j]), h1 = f2bf(v[2 * j + 1]);
    u16 l0 = f2bf(v[2 * j] - bf2f(h0));
    u16 l1 = f2bf(v[2 * j + 1] - bf2f(h1));
    hp[j] = (u32)h0 | ((u32)h1 << 16);
    lp[j] = (u32)l0 | ((u32)l1 << 16);
  }
  ((uint4*)hi)[i] = make_uint4(hp[0], hp[1], hp[2], hp[3]);
  ((uint4*)lo)[i] = make_uint4(lp[0], lp[1], lp[2], lp[3]);
}

// ------------------------------------------- split-bf16 MFMA NT GEMM (r2)
__global__ __launch_bounds__(256) void k_gemm_mfma(
    const u16* __restrict__ Ah, const u16* __restrict__ Al,
    const u16* __restrict__ Bh, const u16* __restrict__ Bl,
    const float* __restrict__ bias, float* __restrict__ C,
    int M, int N, int K) {
  __shared__ __align__(16) u16 sm[4 * 4096];       // Ah | Al | Bh | Bl
  int tid = threadIdx.x;
  int wave = tid >> 6, lane = tid & 63;
  int m0 = blockIdx.y << 7, n0 = blockIdx.x << 7;
  int wr = wave >> 1, wc = wave & 1;
  int l15 = lane & 15, quad = lane >> 4;

  f32x4 acc[4][4];
#pragma unroll
  for (int i = 0; i < 4; i++)
#pragma unroll
    for (int j = 0; j < 4; j++) acc[i][j] = (f32x4){0.f, 0.f, 0.f, 0.f};

  const u16* srcs[4] = {Ah + (size_t)m0 * K, Al + (size_t)m0 * K,
                        Bh + (size_t)n0 * K, Bl + (size_t)n0 * K};
  int li0 = wave * 64 + lane;
  int li1 = li0 + 256;
  int r0 = li0 >> 2, q0 = (li0 & 3) ^ ((r0 >> 1) & 3);
  int r1 = li1 >> 2, q1 = (li1 & 3) ^ ((r1 >> 1) & 3);
  size_t g0 = (size_t)r0 * K + q0 * 8;
  size_t g1 = (size_t)r1 * K + q1 * 8;

  for (int kt = 0; kt < K; kt += 32) {
    __syncthreads();
#pragma unroll
    for (int ri = 0; ri < 4; ri++) {
      const u16* s = srcs[ri] + kt;
      async16(s + g0, &sm[ri * 4096 + wave * 512]);
      async16(s + g1, &sm[ri * 4096 + 2048 + wave * 512]);
    }
    __syncthreads();

    bf16x8 ah[4], al[4], bh[4], bl[4];
#pragma unroll
    for (int i = 0; i < 4; i++) {
      int ra = wr * 64 + i * 16 + l15;
      int qa = (quad ^ ((ra >> 1) & 3)) * 8;
      ah[i] = *(const bf16x8*)&sm[0 * 4096 + ra * 32 + qa];
      al[i] = *(const bf16x8*)&sm[1 * 4096 + ra * 32 + qa];
      int rb = wc * 64 + i * 16 + l15;
      int qb = (quad ^ ((rb >> 1) & 3)) * 8;
      bh[i] = *(const bf16x8*)&sm[2 * 4096 + rb * 32 + qb];
      bl[i] = *(const bf16x8*)&sm[3 * 4096 + rb * 32 + qb];
    }
#pragma unroll
    for (int i = 0; i < 4; i++)
#pragma unroll
      for (int j = 0; j < 4; j++) {
        acc[i][j] = __builtin_amdgcn_mfma_f32_16x16x32_bf16(ah[i], bh[j], acc[i][j], 0, 0, 0);
        acc[i][j] = __builtin_amdgcn_mfma_f32_16x16x32_bf16(ah[i], bl[j], acc[i][j], 0, 0, 0);
        acc[i][j] = __builtin_amdgcn_mfma_f32_16x16x32_bf16(al[i], bh[j], acc[i][j], 0, 0, 0);
      }
  }
#pragma unroll
  for (int i = 0; i < 4; i++) {
    int row0 = m0 + wr * 64 + i * 16 + quad * 4;
#pragma unroll
    for (int j = 0; j < 4; j++) {
      int col = n0 + wc * 64 + j * 16 + l15;
      float bv = bias[col];
#pragma unroll
      for (int r = 0; r < 4; r++)
        C[(size_t)(row0 + r) * N + col] = acc[i][j][r] + bv;
    }
  }
}

// ------------------------------------------- V transpose to padded key space
// Vt[plane][bh][d 96][key' 832] bf16; pads -> 0.  Grid: 64 bh x 13 chunks.
__global__ __launch_bounds__(256) void k_convvt(const float* __restrict__ qkv,
                                                u16* __restrict__ Vthi,
                                                u16* __restrict__ Vtlo) {
  int ck = blockIdx.x % 13;
  int bh = blockIdx.x / 13;
  int b = bh >> 3, h = bh & 7;
  int kt = ck << 6;
  int ve  = kt < 64 ? 50 : kt < 448 ? 439 : 823;   // valid end (padded coords)
  int off = kt < 64 ? 0  : kt < 448 ? 14  : 23;    // key' - off = real n
  __shared__ float Ls[96 * 68];
  int tid = threadIdx.x;
  size_t base = (size_t)b * NTOK;
#pragma unroll
  for (int i = 0; i < 6; i++) {
    int c = i * 256 + tid;            // 1536 = 64 keys x 24 d-chunks
    int key = c / 24, dc = c - key * 24;
    int kp = kt + key;
    float4 v = make_float4(0.f, 0.f, 0.f, 0.f);
    if (kp < ve) {
      int n = kp - off;
      v = *(const float4*)(qkv + (base + n) * QKVD + 2 * DIM + h * HD + dc * 4);
    }
    Ls[(dc * 4 + 0) * 68 + key] = v.x;
    Ls[(dc * 4 + 1) * 68 + key] = v.y;
    Ls[(dc * 4 + 2) * 68 + key] = v.z;
    Ls[(dc * 4 + 3) * 68 + key] = v.w;
  }
  __syncthreads();
#pragma unroll
  for (int i = 0; i < 3; i++) {
    int c = i * 256 + tid;            // 768 = 96 d x 8 key-chunks
    int d = c >> 3, ch = c & 7;
    float4 a = *(const float4*)&Ls[d * 68 + ch * 8];
    float4 e = *(const float4*)&Ls[d * 68 + ch * 8 + 4];
    float xs[8] = {a.x, a.y, a.z, a.w, e.x, e.y, e.z, e.w};
    u32 hp[4], lp[4];
#pragma unroll
    for (int j = 0; j < 4; j++) {
      u32 b0 = asu(xs[2 * j]), b1 = asu(xs[2 * j + 1]);
      hp[j] = (b0 >> 16) | (b1 & 0xffff0000u);
      float l0 = xs[2 * j] - asf(b0 & 0xffff0000u);
      float l1 = xs[2 * j + 1] - asf(b1 & 0xffff0000u);
      lp[j] = (asu(l0) >> 16) | (asu(l1) & 0xffff0000u);
    }
    size_t go = ((size_t)bh * 96 + d) * KPAD + kt + ch * 8;
    *(uint4*)(Vthi + go) = make_uint4(hp[0], hp[1], hp[2], hp[3]);
    *(uint4*)(Vtlo + go) = make_uint4(lp[0], lp[1], lp[2], lp[3]);
  }
}

// ------------------------------------------- MFMA flash attention
// Block: 64 q-rows, 4 waves (16 rows each, Q+O in registers).
// 32-key tiles in PADDED key space; K converted in-kernel fp32->2-plane bf16;
// V staged from pre-transposed global planes via async16; P transposed
// C-layout -> A-layout through per-wave LDS (intra-wave, no barrier).
__global__ __launch_bounds__(256) void k_attn(const float* __restrict__ qkv,
                                              const u16* __restrict__ Vthi,
                                              const u16* __restrict__ Vtlo,
                                              float* __restrict__ outp,
                                              int intra) {
  int t  = blockIdx.x % 13;
  int bh = blockIdx.x / 13;
  int b = bh >> 3, h = bh & 7;

  int seg, q0, qlen;
  if (t == 0)      { seg = 0; q0 = 0;                  qlen = 50; }
  else if (t <= 6) { seg = 1; q0 = 50 + ((t - 1) << 6);  qlen = (425 - q0 < 64) ? (425 - q0) : 64; }
  else             { seg = 2; q0 = 425 + ((t - 7) << 6); qlen = (800 - q0 < 64) ? (800 - q0) : 64; }

  // padded-key-space ranges
  int r0s, r0e, r1s = 0, r1e = 0;
  if (intra) {
    r0s = (seg == 0) ? 0 : (seg == 1) ? 64 : 448;
    r0e = (seg == 0) ? 64 : (seg == 1) ? 448 : 832;
  } else {
    if (seg == 0)      { r0s = 64; r0e = 832; }
    else if (seg == 1) { r0s = 0;  r0e = 64;  r1s = 448; r1e = 832; }
    else               { r0s = 0;  r0e = 448; }
  }
  int n0t = (r0e - r0s) >> 5, n1t = (r1e - r1s) >> 5, nkt = n0t + n1t;

  __shared__ __align__(16) u16 sKh[32 * 96], sKl[32 * 96];   // [key][d]
  __shared__ __align__(16) u16 sVh[96 * 32], sVl[96 * 32];   // [d][key]
  __shared__ u32 sP[4][16][36];                              // per-wave P (hi|lo<<16)

  int tid = threadIdx.x;
  int w = tid >> 6, lane = tid & 63, l15 = lane & 15, quad = lane >> 4;
  size_t base = (size_t)b * NTOK;
  const float sm0 = 0.10206207261596575f;   // 96^-0.5

  // ---- Q fragments (RNE 2-plane, pre-scaled by sm) — registers, once
  bf16x8 qh[3], ql[3];
  {
    int q = q0 + w * 16 + l15; if (q > 799) q = 799;
    const float* qp = qkv + (base + q) * QKVD + h * HD;
#pragma unroll
    for (int df = 0; df < 3; df++) {
      float4 x0v = *(const float4*)(qp + df * 32 + quad * 8);
      float4 x1v = *(const float4*)(qp + df * 32 + quad * 8 + 4);
      float xs[8] = {x0v.x, x0v.y, x0v.z, x0v.w, x1v.x, x1v.y, x1v.z, x1v.w};
#pragma unroll
      for (int j = 0; j < 8; j++) {
        float x = xs[j] * sm0;
        u16 hu = f2bf(x);
        u16 lu = f2bf(x - bf2f(hu));
        qh[df][j] = (short)hu; ql[df][j] = (short)lu;
      }
    }
  }

  f32x4 oacc[6];
#pragma unroll
  for (int c = 0; c < 6; c++) oacc[c] = (f32x4){0.f, 0.f, 0.f, 0.f};
  float m_i[4], l_i[4];
#pragma unroll
  for (int r = 0; r < 4; r++) { m_i[r] = -1e30f; l_i[r] = 0.f; }

  for (int it = 0; it < nkt; it++) {
    int kt = (it < n0t) ? (r0s + (it << 5)) : (r1s + ((it - n0t) << 5));
    int ve  = kt < 64 ? 50 : kt < 448 ? 439 : 823;
    int off = kt < 64 ? 0  : kt < 448 ? 14  : 23;

    __syncthreads();
    // stage K: fp32 -> trunc 2-plane bf16 into LDS [key][d]
#pragma unroll
    for (int i = 0; i < 3; i++) {
      int c = i * 256 + tid;            // 768 = 32 keys x 24 d-chunks
      int key_l = c / 24, dc = c - key_l * 24;
      int n = kt + key_l - off; if (n > 799) n = 799;
      float4 v = *(const float4*)(qkv + (base + n) * QKVD + DIM + h * HD + dc * 4);
      u32 b0 = asu(v.x), b1 = asu(v.y), b2 = asu(v.z), b3 = asu(v.w);
      u32 h01 = (b0 >> 16) | (b1 & 0xffff0000u);
      u32 h23 = (b2 >> 16) | (b3 & 0xffff0000u);
      float l0 = v.x - asf(b0 & 0xffff0000u);
      float l1 = v.y - asf(b1 & 0xffff0000u);
      float l2 = v.z - asf(b2 & 0xffff0000u);
      float l3 = v.w - asf(b3 & 0xffff0000u);
      u32 lo01 = (asu(l0) >> 16) | (asu(l1) & 0xffff0000u);
      u32 lo23 = (asu(l2) >> 16) | (asu(l3) & 0xffff0000u);
      *(uint2*)&sKh[key_l * 96 + dc * 4] = make_uint2(h01, h23);
      *(uint2*)&sKl[key_l * 96 + dc * 4] = make_uint2(lo01, lo23);
    }
    // stage Vt planes via async16 (16B-aligned by padded key space)
#pragma unroll
    for (int i = 0; i < 3; i++) {
      int c = i * 256 + tid;            // 768 chunks: 2 planes x 384
      int plane = c / 384, cc = c - plane * 384;
      int d = cc >> 2, jj = cc & 3;
      const u16* g = (plane ? Vtlo : Vthi) + ((size_t)bh * 96 + d) * KPAD + kt + jj * 8;
      u16* dst = (plane ? sVl : sVh) + (cc << 3);
      async16(g, dst);
    }
    __syncthreads();

    // ---- S = Q K^T via MFMA (rows quad*4+r, col l15 per half)
    f32x4 Sf[2];
#pragma unroll
    for (int h2 = 0; h2 < 2; h2++) {
      f32x4 s = (f32x4){0.f, 0.f, 0.f, 0.f};
      int krow = (h2 * 16 + l15) * 96;
#pragma unroll
      for (int df = 0; df < 3; df++) {
        bf16x8 kh = *(const bf16x8*)&sKh[krow + df * 32 + quad * 8];
        bf16x8 kl = *(const bf16x8*)&sKl[krow + df * 32 + quad * 8];
        s = __builtin_amdgcn_mfma_f32_16x16x32_bf16(qh[df], kh, s, 0, 0, 0);
        s = __builtin_amdgcn_mfma_f32_16x16x32_bf16(ql[df], kh, s, 0, 0, 0);
        s = __builtin_amdgcn_mfma_f32_16x16x32_bf16(qh[df], kl, s, 0, 0, 0);
      }
      Sf[h2] = s;
    }
    if (kt + l15 >= ve)      Sf[0] = (f32x4){-1e30f, -1e30f, -1e30f, -1e30f};
    if (kt + 16 + l15 >= ve) Sf[1] = (f32x4){-1e30f, -1e30f, -1e30f, -1e30f};

    // ---- online softmax
    float mx[4], al[4], ps0[4], ps1[4], rs[4];
#pragma unroll
    for (int r = 0; r < 4; r++) mx[r] = fmaxf(Sf[0][r], Sf[1][r]);
#pragma unroll
    for (int o = 1; o < 16; o <<= 1)
#pragma unroll
      for (int r = 0; r < 4; r++) mx[r] = fmaxf(mx[r], __shfl_xor(mx[r], o, 64));
#pragma unroll
    for (int r = 0; r < 4; r++) {
      float mn = fmaxf(m_i[r], mx[r]);
      al[r] = __expf(m_i[r] - mn);
      m_i[r] = mn;
      ps0[r] = __expf(Sf[0][r] - mn);
      ps1[r] = __expf(Sf[1][r] - mn);
      rs[r] = ps0[r] + ps1[r];
    }
#pragma unroll
    for (int o = 1; o < 16; o <<= 1)
#pragma unroll
      for (int r = 0; r < 4; r++) rs[r] += __shfl_xor(rs[r], o, 64);
#pragma unroll
    for (int r = 0; r < 4; r++) l_i[r] = l_i[r] * al[r] + rs[r];

    // ---- pack P (trunc 2-plane) and transpose via per-wave LDS
#pragma unroll
    for (int r = 0; r < 4; r++) {
      u32 b0 = asu(ps0[r]);
      float lo0 = ps0[r] - asf(b0 & 0xffff0000u);
      sP[w][quad * 4 + r][l15] = (b0 >> 16) | (asu(lo0) & 0xffff0000u);
      u32 b1 = asu(ps1[r]);
      float lo1 = ps1[r] - asf(b1 & 0xffff0000u);
      sP[w][quad * 4 + r][16 + l15] = (b1 >> 16) | (asu(lo1) & 0xffff0000u);
    }
    asm volatile("" ::: "memory");   // intra-wave LDS: HW in-order, stop reordering
    uint4 t0 = *(const uint4*)&sP[w][l15][quad * 8];
    uint4 t1 = *(const uint4*)&sP[w][l15][quad * 8 + 4];
    u32 tt[8] = {t0.x, t0.y, t0.z, t0.w, t1.x, t1.y, t1.z, t1.w};
    bf16x8 ph, pl;
#pragma unroll
    for (int j = 0; j < 8; j++) {
      ph[j] = (short)(tt[j] & 0xffffu);
      pl[j] = (short)(tt[j] >> 16);
    }

    // ---- rescale O, then O += P V via MFMA
    f32x4 alv = {al[0], al[1], al[2], al[3]};
#pragma unroll
    for (int c = 0; c < 6; c++) oacc[c] *= alv;
#pragma unroll
    for (int c = 0; c < 6; c++) {
      int vrow = (c * 16 + l15) * 32 + quad * 8;
      bf16x8 vh = *(const bf16x8*)&sVh[vrow];
      bf16x8 vl = *(const bf16x8*)&sVl[vrow];
      oacc[c] = __builtin_amdgcn_mfma_f32_16x16x32_bf16(ph, vh, oacc[c], 0, 0, 0);
      oacc[c] = __builtin_amdgcn_mfma_f32_16x16x32_bf16(ph, vl, oacc[c], 0, 0, 0);
      oacc[c] = __builtin_amdgcn_mfma_f32_16x16x32_bf16(pl, vh, oacc[c], 0, 0, 0);
    }
  }

  // ---- epilogue
  float inv[4];
#pragma unroll
  for (int r = 0; r < 4; r++) inv[r] = 1.0f / l_i[r];
#pragma unroll
  for (int c = 0; c < 6; c++)
#pragma unroll
    for (int r = 0; r < 4; r++) {
      int rl = w * 16 + quad * 4 + r;
      if (rl < qlen)
        outp[(base + q0 + rl) * DIM + h * HD + c * 16 + l15] = oacc[c][r] * inv[r];
    }
}

// ---------------------------------------------------------------- layernorm
__global__ __launch_bounds__(256) void k_ln(const float* __restrict__ x,
                                            const float* __restrict__ g,
                                            const float* __restrict__ be,
                                            float* __restrict__ outp) {
  int row = blockIdx.x;
  const float* xr = x + (size_t)row * DIM;
  float v[3]; float s = 0.f;
#pragma unroll
  for (int i = 0; i < 3; i++) { v[i] = xr[threadIdx.x + (i << 8)]; s += v[i]; }
#pragma unroll
  for (int off = 1; off < 64; off <<= 1) s += __shfl_xor(s, off, 64);
  __shared__ float red[4];
  int wv = threadIdx.x >> 6;
  if ((threadIdx.x & 63) == 0) red[wv] = s;
  __syncthreads();
  float mu = (red[0] + red[1] + red[2] + red[3]) * (1.0f / 768.0f);
  float sq = 0.f;
#pragma unroll
  for (int i = 0; i < 3; i++) { float d2 = v[i] - mu; sq += d2 * d2; }
#pragma unroll
  for (int off = 1; off < 64; off <<= 1) sq += __shfl_xor(sq, off, 64);
  __syncthreads();
  if ((threadIdx.x & 63) == 0) red[wv] = sq;
  __syncthreads();
  float var = (red[0] + red[1] + red[2] + red[3]) * (1.0f / 768.0f);
  float rstd = rsqrtf(var + 1e-5f);
  float* orow = outp + (size_t)row * DIM;
#pragma unroll
  for (int i = 0; i < 3; i++) {
    int d = threadIdx.x + (i << 8);
    orow[d] = (v[i] - mu) * rstd * g[d] + be[d];
  }
}

// ---------------------------------------------------------------- launch
extern "C" void kernel_launch(void* const* d_in, const int* in_sizes, int n_in,
                              void* d_out, int out_size, void* d_ws, size_t ws_size,
                              hipStream_t stream) {
  (void)in_sizes; (void)n_in; (void)out_size; (void)ws_size;
  const float* seq0 = (const float*)d_in[0];
  const float* seq1 = (const float*)d_in[1];
  const float* seq2 = (const float*)d_in[2];

  const size_t NX   = (size_t)ROWS * DIM;    // 4,915,200
  const size_t NQKV = (size_t)ROWS * QKVD;   // 14,745,600
  const int WIN_N   = QKVD * DIM;            // 1,769,472
  const int WOUT_N  = DIM * DIM;             //   589,824
  const size_t VTN  = (size_t)64 * 96 * KPAD; // 5,111,808 u16 per plane

  // ws layout (~128.2 MiB): x0 | qkv | att | X | S
  //   S region (VTN u16 = 9.75 MiB): WPh/WPl (7.08 MiB) and Vthi time-share it
  //   Vtlo lives in X region (X written only after attention)
  //   P1 planes in att region, P2 planes in x0 region (r2-proven overlaps)
  float* x0   = (float*)d_ws;
  float* qkvb = x0   + NX;
  float* att  = qkvb + NQKV;
  float* X    = att  + NX;
  u16*   S    = (u16*)(X + NX);
  u16*   WPh  = S;          u16* WPl  = S + WIN_N;
  u16*   Vthi = S;          u16* Vtlo = (u16*)X;
  u16*   P1h  = (u16*)att;  u16* P1l  = P1h + NX;
  u16*   P2h  = (u16*)x0;   u16* P2l  = P2h + NX;

  for (int g = 0; g < 2; g++) {           // g=0: inter, g=1: intra
    const float* w_in  = (const float*)d_in[3 + 6 * g];
    const float* b_in  = (const float*)d_in[4 + 6 * g];
    const float* w_out = (const float*)d_in[5 + 6 * g];
    const float* b_out = (const float*)d_in[6 + 6 * g];
    const float* ln_g  = (const float*)d_in[7 + 6 * g];
    const float* ln_b  = (const float*)d_in[8 + 6 * g];

    k_embed<<<ROWS, 256, 0, stream>>>(seq0, seq1, seq2, x0);

    for (int l = 0; l < 4; l++) {
      const float* xin = (l == 0) ? x0 : X;
      k_conv<<<(int)(NX / 8 / 256), 256, 0, stream>>>(xin, P1h, P1l, (int)(NX / 8));
      k_conv<<<WIN_N / 8 / 256, 256, 0, stream>>>(
          w_in + (size_t)l * WIN_N, WPh, WPl, WIN_N / 8);
      k_gemm_mfma<<<dim3(QKVD / 128, ROWS / 128), 256, 0, stream>>>(
          P1h, P1l, WPh, WPl, b_in + (size_t)l * QKVD, qkvb, ROWS, QKVD, DIM);

      k_convvt<<<13 * 64, 256, 0, stream>>>(qkvb, Vthi, Vtlo);
      k_attn<<<13 * 64, 256, 0, stream>>>(qkvb, Vthi, Vtlo, att, g);

      k_conv<<<(int)(NX / 8 / 256), 256, 0, stream>>>(att, P2h, P2l, (int)(NX / 8));
      k_conv<<<WOUT_N / 8 / 256, 256, 0, stream>>>(
          w_out + (size_t)l * WOUT_N, WPh, WPl, WOUT_N / 8);
      k_gemm_mfma<<<dim3(DIM / 128, ROWS / 128), 256, 0, stream>>>(
          P2h, P2l, WPh, WPl, b_out + (size_t)l * DIM, X, ROWS, DIM, DIM);
    }
    k_ln<<<ROWS, 256, 0, stream>>>(X, ln_g, ln_b,
                                   (float*)d_out + (size_t)g * ROWS * DIM);
  }
}